// Round 13
// baseline (20.898 us; speedup 1.0000x reference)
//
#include <hip/hip_runtime.h>
#include <math.h>

// Problem geometry (fixed by the reference)
#define NB 2
#define NVOICE 8
#define NN (NB * NVOICE)   // 16 series
#define NH 64              // harmonics
#define NF 500             // frames
#define NT 32000           // samples
#define NWIN 500           // one 64-sample window per wave
#define WIN 64

// ---- compile-time Hann window table (f64 Taylor cos, rounded to f32) ----
constexpr double kPIO2 = 1.5707963267948966;
constexpr double d_cos_red(double r) {
    double r2 = r * r, term = 1.0, sum = 1.0;
    for (int k = 1; k <= 12; ++k) { term *= -r2 / (double)((2 * k - 1) * (2 * k)); sum += term; }
    return sum;
}
constexpr double d_sin_red(double r) {
    double r2 = r * r, term = r, sum = r;
    for (int k = 1; k <= 12; ++k) { term *= -r2 / (double)((2 * k) * (2 * k + 1)); sum += term; }
    return sum;
}
constexpr double d_cos(double x) {
    int k = 0; double r = x;
    while (r > kPIO2 * 0.5) { r -= kPIO2; ++k; }
    switch (k & 3) {
        case 0: return d_cos_red(r);
        case 1: return -d_sin_red(r);
        case 2: return -d_cos_red(r);
        default: return d_sin_red(r);
    }
}
struct WinT { float wA[64]; float wB[64]; };
constexpr WinT make_win() {
    WinT w{};
    for (int j = 0; j < 64; ++j) {
        float aA = (float)6.283185307179586 * (float)j * 0.0078125f;
        float aB = (float)6.283185307179586 * (float)(j + 64) * 0.0078125f;
        w.wA[j] = 0.5f - 0.5f * (float)d_cos((double)aA);   // win[r]    -> weights frame q+1
        w.wB[j] = 0.5f - 0.5f * (float)d_cos((double)aB);   // win[64+r] -> weights frame q
    }
    return w;
}
constexpr WinT WT = make_win();

// DPP helpers
template<int CTRL, int RMASK>
static __device__ __forceinline__ float dpp0_add(float x) {
    int y = __builtin_amdgcn_update_dpp(0, __float_as_int(x), CTRL, RMASK, 0xF, true);
    return x + __int_as_float(y);
}
// Inclusive 64-lane prefix sum (Hillis-Steele via DPP)
static __device__ __forceinline__ float wave_incl_scan(float x) {
    x = dpp0_add<0x111, 0xF>(x);   // row_shr:1
    x = dpp0_add<0x112, 0xF>(x);   // row_shr:2
    x = dpp0_add<0x114, 0xF>(x);   // row_shr:4
    x = dpp0_add<0x118, 0xF>(x);   // row_shr:8
    x = dpp0_add<0x142, 0xa>(x);   // row_bcast:15 -> rows 1,3
    x = dpp0_add<0x143, 0xc>(x);   // row_bcast:31 -> rows 2,3
    return x;
}
// Full 64-lane sums broadcast to all lanes
static __device__ __forceinline__ float wave_sum_all_f(float x) {
    #pragma unroll
    for (int m = 1; m < 64; m <<= 1) x += __shfl_xor(x, m, 64);
    return x;
}
static __device__ __forceinline__ double wave_sum_all_d(double x) {
    #pragma unroll
    for (int m = 1; m < 64; m <<= 1) x += __shfl_xor(x, m, 64);
    return x;
}

// K_A: one wave per (n, window q). No block barrier, no cross-voice coupling.
// Phase via exact f64 closed form: D(64q) = 64*Sum_{j<q} fr[j] + 8*(fr[q]-fr[q-1]).
__global__ __launch_bounds__(64) void ksynA(const float* __restrict__ freqs,
                                            const float* __restrict__ harms,
                                            const float* __restrict__ amps,
                                            float* __restrict__ vout) {
    int idx = blockIdx.x;              // n * NWIN + q
    int n = idx / NWIN, q = idx % NWIN;
    int l = threadIdx.x;

    __shared__ float4 pb[NH];          // {base_rev, a1, a0, pad} per h (one wave/block)

    int f1 = (q + 1 < NF) ? q + 1 : NF - 1;
    const float* __restrict__ fr = freqs + n * NF;

    // ---- prologue, lane role = h ----
    {
        int h = l;
        float kf = (float)(h + 1);
        // f64 frame prefix: coalesced lane-batches, masked j < q
        double accd = 0.0;
        for (int j0 = 0; j0 < q; j0 += 64) {
            int j = j0 + l;
            float fv = (j < q) ? fr[j] : 0.0f;
            accd += (double)fv;
        }
        double S = wave_sum_all_d(accd);
        double D = 64.0 * S;
        if (q > 0) D += 8.0 * ((double)fr[q] - (double)fr[q - 1]);
        double rk = (double)(h + 1) * (D * (1.0 / 16000.0));  // revolutions at window start
        rk -= floor(rk);
        float base = (float)rk;
        // normalization for frames q, f1 (bit-exact mask, butterfly denom)
        const float* __restrict__ hb = harms + ((size_t)n * NH + h) * NF;
        float fq0 = fr[q], fq1 = fr[f1];
        float hm0 = hb[q], hm1 = hb[f1];
        hm0 = (__fmul_rn(fq0, kf) > 8000.0f) ? 0.0f : hm0;
        hm1 = (__fmul_rn(fq1, kf) > 8000.0f) ? 0.0f : hm1;
        float d0 = wave_sum_all_f(hm0), d1 = wave_sum_all_f(hm1);
        d0 = (d0 == 0.0f) ? 1e-7f : d0;
        d1 = (d1 == 0.0f) ? 1e-7f : d1;
        float va0 = amps[n * NF + q], va1 = amps[n * NF + f1];
        float a0 = __fmul_rn(va0, __fdiv_rn(hm0, d0));
        float a1 = __fmul_rn(va1, __fdiv_rn(hm1, d1));
        pb[h] = make_float4(base, a1, a0, 0.0f);
        // single wave: DS ops retire in order -> no barrier needed
    }

    // ---- main, lane role = sample t = 64q + l ----
    float vAu = fr[(q > 0) ? q - 1 : 0];     // lane-uniform
    float vBu = fr[q];
    float vCu = fr[f1];
    bool mlo   = (l < 32);
    bool mEdge = (q == 0 && mlo) || (q == NF - 1 && !mlo);
    float wy = (float)(mlo ? (2 * l + 65) : (2 * l - 63)) * 0.0078125f;
    float wx = 1.0f - wy;
    if (mEdge) { wx = 1.0f; wy = 0.0f; }     // clamped lerp == fl(vB*k) exactly
    float vLo0 = mEdge ? vBu : (mlo ? vAu : vBu);
    float vLo1 = mEdge ? vBu : (mlo ? vBu : vCu);
    float wA = WT.wA[l], wB = WT.wB[l];

    // in-window base-envelope inclusive scan (phase-tolerant), pre-scaled to rev/k
    float feB = __fadd_rn(__fmul_rn(vLo0, wx), __fmul_rn(vLo1, wy));
    float scanB = wave_incl_scan(feB);
    float scanC = __fmul_rn(scanB, 6.25e-5f);   // = scan/16000: revolutions per unit k

    // live-harmonic bounds (conservative guards; exact mask still applied in band)
    float mxf = fmaxf(fmaxf(vAu, vBu), vCu);
    float mnf = fminf(fminf(vAu, vBu), vCu);
    int hmax = min(64, (int)(__fdiv_rn(8000.5f, mnf)));
    int hA   = min(hmax, (int)(__fdiv_rn(7999.96f, mxf)));
    hmax = __builtin_amdgcn_readfirstlane(hmax);
    hA   = __builtin_amdgcn_readfirstlane(hA);

    float accA = 0.0f, accB = 0.0f;          // audio = wA*accA + wB*accB (factored amp)
    float kf = 1.0f;
    int hh = 0;
    #pragma unroll 4
    for (; hh < hA; ++hh, kf += 1.0f) {      // fe <= 8000 guaranteed: no mask
        float4 pbv = pb[hh];
        float pr = __fmaf_rn(scanC, kf, pbv.x);
        float fr_, sv;
        asm("v_fract_f32 %0, %1" : "=v"(fr_) : "v"(pr));
        asm("v_sin_f32 %0, %1" : "=v"(sv) : "v"(fr_));   // sin(2pi*frac)
        accA = __fmaf_rn(sv, pbv.y, accA);
        accB = __fmaf_rn(sv, pbv.z, accB);
    }
    #pragma unroll 4
    for (; hh < hmax; ++hh, kf += 1.0f) {    // crossing band: bit-exact fe + mask
        float4 pbv = pb[hh];
        float h0 = __fmul_rn(vLo0, kf), h1 = __fmul_rn(vLo1, kf);
        float fe = __fadd_rn(__fmul_rn(h0, wx), __fmul_rn(h1, wy));
        float pr = __fmaf_rn(scanC, kf, pbv.x);
        float fr_, sv;
        asm("v_fract_f32 %0, %1" : "=v"(fr_) : "v"(pr));
        asm("v_sin_f32 %0, %1" : "=v"(sv) : "v"(fr_));
        sv = (fe > 8000.0f) ? 0.0f : sv;     // strict >, bit-exact fe
        accA = __fmaf_rn(sv, pbv.y, accA);
        accB = __fmaf_rn(sv, pbv.z, accB);
    }
    vout[(size_t)n * NT + (q << 6) + l] = __fadd_rn(__fmul_rn(accA, wA), __fmul_rn(accB, wB));
}

// K_B: out[b][t] = 0.02 * sum_{v=0..7} vout[b*8+v][t]   (fixed order: deterministic,
// same order as the previous in-block epilogue -> bit-identical)
__global__ __launch_bounds__(256) void ksumB(const float* __restrict__ vout,
                                             float* __restrict__ out) {
    int t = blockIdx.x * 256 + threadIdx.x;      // [0, NB*NT)
    int b = t / NT, tt = t - b * NT;
    const float* __restrict__ vb = vout + (size_t)(b * NVOICE) * NT + tt;
    float acc = 0.0f;
    #pragma unroll
    for (int v = 0; v < NVOICE; ++v) acc = __fadd_rn(acc, vb[(size_t)v * NT]);
    out[t] = __fmul_rn(0.02f, acc);
}

extern "C" void kernel_launch(void* const* d_in, const int* in_sizes, int n_in,
                              void* d_out, int out_size, void* d_ws, size_t ws_size,
                              hipStream_t stream) {
    (void)in_sizes; (void)n_in; (void)out_size; (void)ws_size;
    const float* freqs = (const float*)d_in[0];   // (2,8,500)
    const float* harms = (const float*)d_in[1];   // (2,8,64,500)
    const float* amps  = (const float*)d_in[2];   // (2,8,500)
    float* out = (float*)d_out;                   // (2,32000)

    float* vout = (float*)d_ws;                   // [NN][NT] = 2 MB, fully overwritten

    hipLaunchKernelGGL(ksynA, dim3(NN * NWIN), dim3(64), 0, stream,
                       freqs, harms, amps, vout);
    hipLaunchKernelGGL(ksumB, dim3((NB * NT) / 256), dim3(256), 0, stream,
                       vout, out);
}

// Round 14
// 14.183 us; speedup vs baseline: 1.4735x; 1.4735x over previous
//
#include <hip/hip_runtime.h>
#include <math.h>

// Problem geometry (fixed by the reference)
#define NB 2
#define NVOICE 8
#define NN (NB * NVOICE)   // 16 series
#define NH 64              // harmonics
#define NF 500             // frames
#define NT 32000           // samples
#define NWIN 500           // one 64-sample window per block
#define WIN 64

// ---- compile-time Hann window table (f64 Taylor cos, rounded to f32) ----
constexpr double kPIO2 = 1.5707963267948966;
constexpr double d_cos_red(double r) {
    double r2 = r * r, term = 1.0, sum = 1.0;
    for (int k = 1; k <= 12; ++k) { term *= -r2 / (double)((2 * k - 1) * (2 * k)); sum += term; }
    return sum;
}
constexpr double d_sin_red(double r) {
    double r2 = r * r, term = r, sum = r;
    for (int k = 1; k <= 12; ++k) { term *= -r2 / (double)((2 * k) * (2 * k + 1)); sum += term; }
    return sum;
}
constexpr double d_cos(double x) {
    int k = 0; double r = x;
    while (r > kPIO2 * 0.5) { r -= kPIO2; ++k; }
    switch (k & 3) {
        case 0: return d_cos_red(r);
        case 1: return -d_sin_red(r);
        case 2: return -d_cos_red(r);
        default: return d_sin_red(r);
    }
}
struct WinT { float wA[64]; float wB[64]; };
constexpr WinT make_win() {
    WinT w{};
    for (int j = 0; j < 64; ++j) {
        float aA = (float)6.283185307179586 * (float)j * 0.0078125f;
        float aB = (float)6.283185307179586 * (float)(j + 64) * 0.0078125f;
        w.wA[j] = 0.5f - 0.5f * (float)d_cos((double)aA);   // win[r]    -> weights frame q+1
        w.wB[j] = 0.5f - 0.5f * (float)d_cos((double)aB);   // win[64+r] -> weights frame q
    }
    return w;
}
constexpr WinT WT = make_win();

// DPP helpers
template<int CTRL, int RMASK>
static __device__ __forceinline__ float dpp0_add(float x) {
    int y = __builtin_amdgcn_update_dpp(0, __float_as_int(x), CTRL, RMASK, 0xF, true);
    return x + __int_as_float(y);
}
// Inclusive 64-lane prefix sum (Hillis-Steele via DPP)
static __device__ __forceinline__ float wave_incl_scan(float x) {
    x = dpp0_add<0x111, 0xF>(x);   // row_shr:1
    x = dpp0_add<0x112, 0xF>(x);   // row_shr:2
    x = dpp0_add<0x114, 0xF>(x);   // row_shr:4
    x = dpp0_add<0x118, 0xF>(x);   // row_shr:8
    x = dpp0_add<0x142, 0xa>(x);   // row_bcast:15 -> rows 1,3
    x = dpp0_add<0x143, 0xc>(x);   // row_bcast:31 -> rows 2,3
    return x;
}
// Full 64-lane sums broadcast to all lanes (prologue only)
static __device__ __forceinline__ float wave_sum_all_f(float x) {
    #pragma unroll
    for (int m = 1; m < 64; m <<= 1) x += __shfl_xor(x, m, 64);
    return x;
}
static __device__ __forceinline__ double wave_sum_all_d(double x) {
    #pragma unroll
    for (int m = 1; m < 64; m <<= 1) x += __shfl_xor(x, m, 64);
    return x;
}

// Fused kernel: block = (b, window q); 512 thr = 8 voices x 64 lanes.
// Phase: exact f64 closed form D(64q) = 64*Sum_{j<q} fr[j] + 8*(fr[q]-fr[q-1]);
// per-harmonic sin via Chebyshev recurrence s_k = 2cos(theta)*s_{k-1} - s_{k-2}.
__global__ __launch_bounds__(512) void ksyn_all(const float* __restrict__ freqs,
                                                const float* __restrict__ harms,
                                                const float* __restrict__ amps,
                                                float* __restrict__ out) {
    int q = blockIdx.x % NWIN;
    int b = blockIdx.x / NWIN;
    int tid = threadIdx.x;
    int v = tid >> 6, l = tid & 63;
    int n = (b << 3) + v;

    __shared__ float2 pb[NVOICE][NH];      // {a1, a0} per (voice,h)
    __shared__ float vsum[NVOICE][WIN];    // per-voice audio

    int f1 = (q + 1 < NF) ? q + 1 : NF - 1;
    const float* __restrict__ fr = freqs + n * NF;

    // ---- wave-uniform f64 frame prefix D0 (coalesced lane-batches, masked j<q)
    double D0;
    {
        double accd = 0.0;
        for (int j0 = 0; j0 < q; j0 += 64) {
            int j = j0 + l;
            float fv = (j < q) ? fr[j] : 0.0f;
            accd += (double)fv;
        }
        double S = wave_sum_all_d(accd);
        D0 = 64.0 * S;
        if (q > 0) D0 += 8.0 * ((double)fr[q] - (double)fr[q - 1]);
    }

    // ---- prologue, lane role = h: normalization (bit-exact mask, butterfly denom)
    {
        int h = l;
        float kf = (float)(h + 1);
        const float* __restrict__ hb = harms + ((size_t)n * NH + h) * NF;
        float fq0 = fr[q], fq1 = fr[f1];
        float hm0 = hb[q], hm1 = hb[f1];
        hm0 = (__fmul_rn(fq0, kf) > 8000.0f) ? 0.0f : hm0;
        hm1 = (__fmul_rn(fq1, kf) > 8000.0f) ? 0.0f : hm1;
        float d0 = wave_sum_all_f(hm0), d1 = wave_sum_all_f(hm1);
        d0 = (d0 == 0.0f) ? 1e-7f : d0;
        d1 = (d1 == 0.0f) ? 1e-7f : d1;
        float va0 = amps[n * NF + q], va1 = amps[n * NF + f1];
        float a0 = __fmul_rn(va0, __fdiv_rn(hm0, d0));
        float a1 = __fmul_rn(va1, __fdiv_rn(hm1, d1));
        pb[v][h] = make_float2(a1, a0);
        // wave-private LDS row; DS ops retire in order per wave -> no block barrier
    }

    // ---- main, lane role = sample t = 64q + l ----
    float vAu = fr[(q > 0) ? q - 1 : 0];     // lane-uniform
    float vBu = fr[q];
    float vCu = fr[f1];
    bool mlo   = (l < 32);
    bool mEdge = (q == 0 && mlo) || (q == NF - 1 && !mlo);
    float wy = (float)(mlo ? (2 * l + 65) : (2 * l - 63)) * 0.0078125f;
    float wx = 1.0f - wy;
    if (mEdge) { wx = 1.0f; wy = 0.0f; }     // clamped lerp == fl(vB*k) exactly
    float vLo0 = mEdge ? vBu : (mlo ? vAu : vBu);
    float vLo1 = mEdge ? vBu : (mlo ? vBu : vCu);
    float wA = WT.wA[l], wB = WT.wB[l];

    // in-window base-envelope inclusive scan (phase-tolerant)
    float feB = __fadd_rn(__fmul_rn(vLo0, wx), __fmul_rn(vLo1, wy));
    float scanB = wave_incl_scan(feB);

    // per-lane fundamental phase (revolutions), f64 fract for precision
    float phiF;
    {
        double Phid = (D0 + (double)scanB) * (1.0 / 16000.0);
        Phid -= floor(Phid);
        phiF = (float)Phid;
    }
    float sp, cp;
    asm("v_sin_f32 %0, %1" : "=v"(sp) : "v"(phiF));   // sin(2pi*phi)
    asm("v_cos_f32 %0, %1" : "=v"(cp) : "v"(phiF));   // cos(2pi*phi)
    float c2 = __fadd_rn(cp, cp);

    // live-harmonic bounds (conservative guards; exact mask still applied in band)
    float mxf = fmaxf(fmaxf(vAu, vBu), vCu);
    float mnf = fminf(fminf(vAu, vBu), vCu);
    int hmax = min(64, (int)(__fdiv_rn(8000.5f, mnf)));
    int hA   = min(hmax, (int)(__fdiv_rn(7999.96f, mxf)));
    hmax = __builtin_amdgcn_readfirstlane(hmax);
    hA   = __builtin_amdgcn_readfirstlane(hA);

    const float2* __restrict__ pbRow = pb[v];
    float accA = 0.0f, accB = 0.0f;          // audio = wA*accA + wB*accB (factored amp)
    float skm1 = 0.0f, sk = sp;              // s_0 = 0, s_1 = sin(theta)
    int hh = 0;
    #pragma unroll 4
    for (; hh < hA; ++hh) {                  // fe <= 8000 guaranteed: no mask
        float2 a = pbRow[hh];
        accA = __fmaf_rn(sk, a.x, accA);
        accB = __fmaf_rn(sk, a.y, accB);
        float sn = __fmaf_rn(c2, sk, -skm1); // Chebyshev step
        skm1 = sk; sk = sn;
    }
    float kfv = (float)(hA + 1);
    #pragma unroll 4
    for (; hh < hmax; ++hh, kfv += 1.0f) {   // crossing band: bit-exact fe + mask
        float2 a = pbRow[hh];
        float h0 = __fmul_rn(vLo0, kfv), h1 = __fmul_rn(vLo1, kfv);
        float fe = __fadd_rn(__fmul_rn(h0, wx), __fmul_rn(h1, wy));
        float sv = (fe > 8000.0f) ? 0.0f : sk;   // strict >, bit-exact fe
        accA = __fmaf_rn(sv, a.x, accA);
        accB = __fmaf_rn(sv, a.y, accB);
        float sn = __fmaf_rn(c2, sk, -skm1);
        skm1 = sk; sk = sn;
    }
    vsum[v][l] = __fadd_rn(__fmul_rn(accA, wA), __fmul_rn(accB, wB));
    __syncthreads();

    if (tid < WIN) {
        float s8 = 0.0f;
        #pragma unroll
        for (int vv = 0; vv < NVOICE; ++vv) s8 = __fadd_rn(s8, vsum[vv][tid]);
        out[(size_t)b * NT + (q << 6) + tid] = __fmul_rn(0.02f, s8);
    }
}

extern "C" void kernel_launch(void* const* d_in, const int* in_sizes, int n_in,
                              void* d_out, int out_size, void* d_ws, size_t ws_size,
                              hipStream_t stream) {
    (void)in_sizes; (void)n_in; (void)out_size; (void)d_ws; (void)ws_size;
    const float* freqs = (const float*)d_in[0];   // (2,8,500)
    const float* harms = (const float*)d_in[1];   // (2,8,64,500)
    const float* amps  = (const float*)d_in[2];   // (2,8,500)
    float* out = (float*)d_out;                   // (2,32000)

    hipLaunchKernelGGL(ksyn_all, dim3(NB * NWIN), dim3(512), 0, stream,
                       freqs, harms, amps, out);
}